// Round 10
// baseline (976.113 us; speedup 1.0000x reference)
//
#include <hip/hip_runtime.h>
#include <stdint.h>

// LSTM cell: B=8192, DIN=1024, DOUT=1024, fp32 in/out.
// R10: R6's 4-phase calendar at BK=32 -> 64KB LDS -> TWO blocks/CU.
// Co-resident blocks desync naturally (m114 mechanism): one block's
// read/barrier regions overlap the other's MFMA regions.
// Phase roles (tiles t=2i->buf0, u=2i+1->buf1, v=2i+2, w=2i+3):
//   Ph0: STA(1,u);  LDBA(0)+LDAH(0,0); LG0; MMH(0); BAR
//   Ph1: STB(0,v);  LDAH(1,0);         LG0; MMH(1); VMC(2); BAR  [pub tile u]
//   Ph2: STA(0,v);  LDBA(1)+LDAH(0,1); LG0; MMH(0); BAR
//   Ph3: STB(1,w);  LDAH(1,1);         LG0; MMH(1); VMC(2); BAR  [pub tile v]
// WAR: each stage target's last reader drained by the previous phase's
// LG0+BAR (Ph0->sA1: prev Ph3 reads; Ph1->sB0: Ph0; Ph2->sA0: Ph1; Ph3->sB1: Ph2).
// RAW: VMC(2) at Ph1-end (outstanding B(u)2,A(u)2,B(v)2=6 -> completes
// B(u)+A(u)) publishes buf1; VMC(2) at Ph3-end publishes buf0. Last iter:
// no v/w stages, Ph1 uses VMC(0) to complete tile 63.
// BK=32 swizzle (R9-verified): phys_slot = slot ^ ((row>>1)&3);
//   read roff = ((l4 ^ ((l15>>1)&3))<<3); stage src k-perm ((t&3)^((t>>3)&3))*8.

typedef __attribute__((ext_vector_type(8))) _Float16 half8;
typedef __attribute__((ext_vector_type(4))) _Float16 half4;
typedef __attribute__((ext_vector_type(4))) float f32x4;

__device__ __forceinline__ void gload_lds16(const void* g, void* l) {
  __builtin_amdgcn_global_load_lds(
      (const __attribute__((address_space(1))) void*)g,
      (__attribute__((address_space(3))) void*)l, 16, 0, 0);
}

__device__ __forceinline__ float sigf(float x) { return 1.0f / (1.0f + __expf(-x)); }
__device__ __forceinline__ float tanhf_(float x) { return 1.0f - 2.0f / (__expf(2.0f * x) + 1.0f); }

#define FENCE asm volatile("" ::: "memory")
#define BAR do { FENCE; __builtin_amdgcn_s_barrier(); FENCE; } while (0)
#define LG0 do { asm volatile("s_waitcnt lgkmcnt(0)" ::: "memory"); \
                 __builtin_amdgcn_sched_barrier(0); } while (0)
#define VMC(n) asm volatile("s_waitcnt vmcnt(" #n ")" ::: "memory")

// ---------------- merged packing kernel ----------------
// blocks [0,8192): Wt pack; [8192,16384): Xh pack; [16384,16400): bias.
// Wt[n'][k], n' = (j>>4)*64 + g*16 + (j&15); k<1024 -> Wx_g[k][j], else Wh_g.
__global__ void lstm_pack_all(const float* __restrict__ x, const float* __restrict__ h,
                              const float* __restrict__ Wxi, const float* __restrict__ Whi,
                              const float* __restrict__ Wxf, const float* __restrict__ Whf,
                              const float* __restrict__ Wxg, const float* __restrict__ Whg,
                              const float* __restrict__ Wxo, const float* __restrict__ Who,
                              const float* __restrict__ bxi, const float* __restrict__ bhi,
                              const float* __restrict__ bxf, const float* __restrict__ bhf,
                              const float* __restrict__ bxg, const float* __restrict__ bhg,
                              const float* __restrict__ bxo, const float* __restrict__ bho,
                              _Float16* __restrict__ Wt, _Float16* __restrict__ Xh,
                              float* __restrict__ bias) {
  __shared__ float tile[32][33];
  int b = blockIdx.x;
  int t = threadIdx.x;
  if (b < 8192) {
    int nt = b & 127, kt = b >> 7;
    int g = nt & 3, jt32 = nt >> 2;
    const float* Wx[4] = {Wxi, Wxf, Wxg, Wxo};
    const float* Wh[4] = {Whi, Whf, Whg, Who};
    int k0 = kt * 32;
    const float* src = (k0 < 1024) ? (Wx[g] + (size_t)k0 * 1024)
                                   : (Wh[g] + (size_t)(k0 - 1024) * 1024);
    int j0 = jt32 * 32;
    int cc = t & 31, r0 = t >> 5;
    #pragma unroll
    for (int p = 0; p < 4; ++p) {
      int r = p * 8 + r0;
      tile[r][cc] = src[(size_t)r * 1024 + j0 + cc];
    }
    __syncthreads();
    int jj = t >> 3, kk = (t & 7) * 4;
    int j = j0 + jj;
    int np = ((j >> 4) << 6) + g * 16 + (j & 15);
    half4 v;
    v[0] = (_Float16)tile[kk + 0][jj];
    v[1] = (_Float16)tile[kk + 1][jj];
    v[2] = (_Float16)tile[kk + 2][jj];
    v[3] = (_Float16)tile[kk + 3][jj];
    *(half4*)(Wt + (size_t)np * 2048 + k0 + kk) = v;
  } else if (b < 16384) {
    size_t tt = (size_t)(b - 8192) * 256 + t;
    size_t e = tt * 8;
    int row = (int)(e >> 11), k = (int)(e & 2047);
    const float* src = (k < 1024) ? (x + (size_t)row * 1024 + k)
                                  : (h + (size_t)row * 1024 + (k - 1024));
    float4 f0 = *(const float4*)src;
    float4 f1 = *(const float4*)(src + 4);
    half8 v;
    v[0] = (_Float16)f0.x; v[1] = (_Float16)f0.y; v[2] = (_Float16)f0.z; v[3] = (_Float16)f0.w;
    v[4] = (_Float16)f1.x; v[5] = (_Float16)f1.y; v[6] = (_Float16)f1.z; v[7] = (_Float16)f1.w;
    *(half8*)(Xh + e) = v;
  } else {
    int tt = (b - 16384) * 256 + t;
    if (tt < 4096) {
      const float* bx[4] = {bxi, bxf, bxg, bxo};
      const float* bh[4] = {bhi, bhf, bhg, bho};
      int q = tt >> 4, r = tt & 15;
      int g = q & 3, j = (q >> 2) * 16 + r;
      bias[tt] = bx[g][j] + bh[g][j];
    }
  }
}

// ---------------- 4-phase BK=32 fused GEMM, 2 blocks/CU ----------------
__global__ __launch_bounds__(512, 4) void lstm_gemm_r10(
    const _Float16* __restrict__ Xh, const _Float16* __restrict__ Wt,
    const float* __restrict__ c, const float* __restrict__ bias,
    float* __restrict__ out) {
  __shared__ ushort sA[2][256 * 32];   // 16KB x2
  __shared__ ushort sB[2][256 * 32];   // 16KB x2  -> 64KB total

  int bid = blockIdx.x;                 // 512 blocks = 2/CU, single round
  int xcd = bid & 7, idx = bid >> 3;
  int mt = (xcd >> 1) * 8 + (idx >> 3); // 0..31
  int jt = (xcd & 1) * 8 + (idx & 7);   // 0..15
  int brow0 = mt * 256, bcol0 = jt * 256;

  int tid = threadIdx.x, lane = tid & 63, wave = tid >> 6;
  int wr = wave >> 2, wc = wave & 3;
  int l15 = lane & 15, l4 = lane >> 4;

  f32x4 acc[8][4] = {};                 // [m-frag 0..7][gate]

  // read-side swizzle offset (elems): phys_slot = l4 ^ ((l15>>1)&3)
  int roff = ((l4 ^ ((l15 >> 1) & 3)) << 3);
  int aoff0 = (wr * 128 + l15) * 32;
  int boff0 = (wc * 64 + l15) * 32;
  // stage-side source k-permutation (matching involution)
  int ssl = (((tid & 3) ^ ((tid >> 3) & 3)) << 3);
  int srow = tid >> 2;                  // 0..127 per call

  auto stA = [&](int buf, int t, int a) {
    const _Float16* src = Xh + (size_t)(brow0 + a * 128 + srow) * 2048 + t * 32 + ssl;
    gload_lds16(src, &sA[buf][(a * 128 + wave * 16) * 32]);
  };
  auto stB = [&](int buf, int t, int a) {
    const _Float16* src = Wt + (size_t)(bcol0 + a * 128 + srow) * 2048 + t * 32 + ssl;
    gload_lds16(src, &sB[buf][(a * 128 + wave * 16) * 32]);
  };

#define STA(buf, t) do { stA(buf, t, 0); stA(buf, t, 1); } while (0)
#define STB(buf, t) do { stB(buf, t, 0); stB(buf, t, 1); } while (0)

#define LDBA(BUF) do { _Pragma("unroll") for (int nf = 0; nf < 4; ++nf) \
    bf[nf] = *(const half8*)&sB[BUF][boff0 + nf * 512 + roff]; } while (0)
#define LDAH(mh, BUF) do { _Pragma("unroll") for (int mi = 0; mi < 4; ++mi) \
    af[mi] = *(const half8*)&sA[BUF][aoff0 + ((mh) * 4 + mi) * 512 + roff]; } while (0)
#define MMH(mh) do {                                                          \
    __builtin_amdgcn_s_setprio(1);                                            \
    _Pragma("unroll") for (int mi = 0; mi < 4; ++mi)                          \
    _Pragma("unroll") for (int nf = 0; nf < 4; ++nf)                          \
      acc[(mh) * 4 + mi][nf] = __builtin_amdgcn_mfma_f32_16x16x32_f16(        \
          af[mi], bf[nf], acc[(mh) * 4 + mi][nf], 0, 0, 0);                   \
    __builtin_amdgcn_s_setprio(0); } while (0)

  // Prologue: tile0 (A+B) -> buf0, tile1 B -> buf1; complete tile0.
  STA(0, 0); STB(0, 0); STB(1, 1);
  VMC(2);                               // completes A(0)+B(0); B(1) may fly
  BAR;

  half8 af[4], bf[4];

#pragma unroll 1
  for (int i = 0; i < 32; ++i) {
    const int u = 2 * i + 1, v = 2 * i + 2, w = 2 * i + 3;
    const bool pf = (i < 31);

    // Ph0: buf0 mh0.  Stage A(u)->buf1.
    STA(1, u);
    LDBA(0); LDAH(0, 0);
    LG0; MMH(0);
    BAR;
    // Ph1: buf0 mh1.  Stage B(v)->buf0.  Publish tile u.
    if (pf) STB(0, v);
    LDAH(1, 0);
    LG0; MMH(1);
    if (pf) { VMC(2); }
    else    { VMC(0); }
    BAR;
    // Ph2: buf1 mh0.  Stage A(v)->buf0.
    if (pf) STA(0, v);
    LDBA(1); LDAH(0, 1);
    LG0; MMH(0);
    BAR;
    // Ph3: buf1 mh1.  Stage B(w)->buf1.  Publish tile v.
    if (pf) STB(1, w);
    LDAH(1, 1);
    LG0; MMH(1);
    if (pf) { VMC(2); }
    BAR;
  }
#undef STA
#undef STB
#undef LDBA
#undef LDAH
#undef MMH

  // ---- fused LSTM epilogue (4 gates = 4 n-frags of this wave) ----
  int j = jt * 64 + wc * 16 + l15;
  int nbase = bcol0 + wc * 64 + l15;
  float bi  = bias[nbase + 0];
  float bff = bias[nbase + 16];
  float bg  = bias[nbase + 32];
  float bo  = bias[nbase + 48];
  float* hout = out;
  float* cout = out + (size_t)8192 * 1024;
  #pragma unroll
  for (int m = 0; m < 8; ++m) {
    #pragma unroll
    for (int r = 0; r < 4; ++r) {
      int grow = brow0 + wr * 128 + m * 16 + l4 * 4 + r;
      size_t o = (size_t)grow * 1024 + j;
      float zi = acc[m][0][r] + bi;
      float zf = acc[m][1][r] + bff;
      float zg = acc[m][2][r] + bg;
      float zo = acc[m][3][r] + bo;
      float ig = sigf(zi);
      float fg = sigf(zf);
      float gg = tanhf_(zg);
      float og = sigf(zo);
      float cold = c[o];
      float cn = fg * cold + ig * gg;
      hout[o] = og * tanhf_(cn);
      cout[o] = cn;
    }
  }
}

// ---------------- fallback path (round-1, validated) ----------------

__global__ void lstm_pack_w_v1(const float* __restrict__ Wxi, const float* __restrict__ Whi,
                               const float* __restrict__ Wxf, const float* __restrict__ Whf,
                               const float* __restrict__ Wxg, const float* __restrict__ Whg,
                               const float* __restrict__ Wxo, const float* __restrict__ Who,
                               _Float16* __restrict__ Wt) {
  __shared__ float tile[32][33];
  int nt = blockIdx.x;
  int kt = blockIdx.y;
  int g = nt & 3, jt = nt >> 2;
  const float* Wx[4] = {Wxi, Wxf, Wxg, Wxo};
  const float* Wh[4] = {Whi, Whf, Whg, Who};
  int k0 = kt * 32;
  const float* src = (k0 < 1024) ? (Wx[g] + (size_t)k0 * 1024)
                                 : (Wh[g] + (size_t)(k0 - 1024) * 1024);
  int j0 = jt * 32;
  int t = threadIdx.x;
  int cc = t & 31, r0 = t >> 5;
  #pragma unroll
  for (int p = 0; p < 4; ++p) {
    int r = p * 8 + r0;
    tile[r][cc] = src[(size_t)r * 1024 + j0 + cc];
  }
  __syncthreads();
  int jj = t >> 3, kk = (t & 7) * 4;
  half4 v;
  v[0] = (_Float16)tile[kk + 0][jj];
  v[1] = (_Float16)tile[kk + 1][jj];
  v[2] = (_Float16)tile[kk + 2][jj];
  v[3] = (_Float16)tile[kk + 3][jj];
  _Float16* dst = Wt + (size_t)(nt * 32 + jj) * 2048 + k0 + kk;
  *(half4*)dst = v;
}

__global__ void lstm_pack_bias_v1(const float* __restrict__ bxi, const float* __restrict__ bhi,
                                  const float* __restrict__ bxf, const float* __restrict__ bhf,
                                  const float* __restrict__ bxg, const float* __restrict__ bhg,
                                  const float* __restrict__ bxo, const float* __restrict__ bho,
                                  float* __restrict__ bias) {
  int t = blockIdx.x * 256 + threadIdx.x;
  if (t >= 4096) return;
  const float* bx[4] = {bxi, bxf, bxg, bxo};
  const float* bh[4] = {bhi, bhf, bhg, bho};
  int jt = t >> 7, g = (t >> 5) & 3, jj = t & 31;
  int j = jt * 32 + jj;
  bias[t] = bx[g][j] + bh[g][j];
}

__global__ __launch_bounds__(256, 2) void lstm_gemm_v1(
    const float* __restrict__ x, const float* __restrict__ h, const float* __restrict__ c,
    const _Float16* __restrict__ Wt, const float* __restrict__ bias,
    float* __restrict__ out) {
  __shared__ ushort sA[128 * 64];
  __shared__ ushort sB[128 * 64];
  int bid = blockIdx.x;
  int sbid = (bid & 7) * 256 + (bid >> 3);
  int mt = sbid >> 5, jt = sbid & 31;
  int brow0 = mt * 128;
  int tid = threadIdx.x;
  int lane = tid & 63, wave = tid >> 6;
  int wr = wave >> 1, wc = wave & 1;
  f32x4 acc[4][4] = {};
  int ar = tid >> 3;
  int as = tid & 7;
  int l3 = lane >> 3, l7w = lane & 7;
  int bsw = ((l7w ^ l3) << 3);
  int l15 = lane & 15, l4 = lane >> 4, l7 = lane & 7;
  for (int kt = 0; kt < 32; ++kt) {
    int k0 = kt * 64;
    const float* asrc = (k0 < 1024) ? (x + k0) : (h + (k0 - 1024));
    #pragma unroll
    for (int stp = 0; stp < 4; ++stp) {
      int row = stp * 32 + ar;
      const float* p = asrc + (size_t)(brow0 + row) * 1024 + as * 8;
      float4 f0 = *(const float4*)p;
      float4 f1 = *(const float4*)(p + 4);
      half8 hv;
      hv[0] = (_Float16)f0.x; hv[1] = (_Float16)f0.y;
      hv[2] = (_Float16)f0.z; hv[3] = (_Float16)f0.w;
      hv[4] = (_Float16)f1.x; hv[5] = (_Float16)f1.y;
      hv[6] = (_Float16)f1.z; hv[7] = (_Float16)f1.w;
      *(half8*)&sA[row * 64 + ((as ^ (row & 7)) << 3)] = hv;
    }
    #pragma unroll
    for (int ccall = 0; ccall < 4; ++ccall) {
      int rowbase = ccall * 32 + wave * 8;
      int grow = jt * 128 + rowbase + l3;
      const _Float16* src = Wt + (size_t)grow * 2048 + k0 + bsw;
      gload_lds16(src, &sB[rowbase * 64]);
    }
    __syncthreads();
    #pragma unroll
    for (int ks = 0; ks < 2; ++ks) {
      half8 af[4], bfr[4];
      #pragma unroll
      for (int mi = 0; mi < 4; ++mi) {
        int row = wr * 64 + mi * 16 + l15;
        af[mi] = *(const half8*)&sA[row * 64 + (((ks * 4 + l4) ^ l7) << 3)];
      }
      #pragma unroll
      for (int g = 0; g < 4; ++g) {
        int nr = g * 32 + wc * 16 + l15;
        bfr[g] = *(const half8*)&sB[nr * 64 + (((ks * 4 + l4) ^ l7) << 3)];
      }
      #pragma unroll
      for (int mi = 0; mi < 4; ++mi)
        #pragma unroll
        for (int g = 0; g < 4; ++g)
          acc[mi][g] = __builtin_amdgcn_mfma_f32_16x16x32_f16(af[mi], bfr[g], acc[mi][g], 0, 0, 0);
    }
    __syncthreads();
  }
  int j = jt * 32 + wc * 16 + l15;
  int nb = jt * 128 + wc * 16 + l15;
  float bi  = bias[nb + 0];
  float bff = bias[nb + 32];
  float bg  = bias[nb + 64];
  float bo  = bias[nb + 96];
  float* hout = out;
  float* cout = out + (size_t)8192 * 1024;
  #pragma unroll
  for (int mi = 0; mi < 4; ++mi) {
    #pragma unroll
    for (int r = 0; r < 4; ++r) {
      int grow = brow0 + wr * 64 + mi * 16 + l4 * 4 + r;
      size_t idx = (size_t)grow * 1024 + j;
      float zi = acc[mi][0][r] + bi;
      float zf = acc[mi][1][r] + bff;
      float zg = acc[mi][2][r] + bg;
      float zo = acc[mi][3][r] + bo;
      float ig = sigf(zi);
      float fg = sigf(zf);
      float gg = tanhf_(zg);
      float og = sigf(zo);
      float cold = c[idx];
      float cn = fg * cold + ig * gg;
      hout[idx] = og * tanhf_(cn);
      cout[idx] = cn;
    }
  }
}

extern "C" void kernel_launch(void* const* d_in, const int* in_sizes, int n_in,
                              void* d_out, int out_size, void* d_ws, size_t ws_size,
                              hipStream_t stream) {
  const float* x   = (const float*)d_in[0];
  const float* h   = (const float*)d_in[1];
  const float* c   = (const float*)d_in[2];
  const float* Wxi = (const float*)d_in[3];
  const float* Whi = (const float*)d_in[4];
  const float* bxi = (const float*)d_in[5];
  const float* bhi = (const float*)d_in[6];
  const float* Wxf = (const float*)d_in[7];
  const float* Whf = (const float*)d_in[8];
  const float* bxf = (const float*)d_in[9];
  const float* bhf = (const float*)d_in[10];
  const float* Wxg = (const float*)d_in[11];
  const float* Whg = (const float*)d_in[12];
  const float* bxg = (const float*)d_in[13];
  const float* bhg = (const float*)d_in[14];
  const float* Wxo = (const float*)d_in[15];
  const float* Who = (const float*)d_in[16];
  const float* bxo = (const float*)d_in[17];
  const float* bho = (const float*)d_in[18];
  float* out = (float*)d_out;

  const size_t WT_BYTES = (size_t)4096 * 2048 * 2;   // 16 MiB
  const size_t XH_BYTES = (size_t)8192 * 2048 * 2;   // 32 MiB
  const size_t NEED = WT_BYTES + XH_BYTES + 4096 * 4;

  if (ws_size >= NEED) {
    _Float16* Wt = (_Float16*)d_ws;
    _Float16* Xh = (_Float16*)((char*)d_ws + WT_BYTES);
    float* bias  = (float*)((char*)d_ws + WT_BYTES + XH_BYTES);
    lstm_pack_all<<<16400, 256, 0, stream>>>(x, h, Wxi, Whi, Wxf, Whf, Wxg, Whg,
                                             Wxo, Who, bxi, bhi, bxf, bhf,
                                             bxg, bhg, bxo, bho, Wt, Xh, bias);
    lstm_gemm_r10<<<512, 512, 0, stream>>>(Xh, Wt, c, bias, out);
  } else {
    _Float16* Wt = (_Float16*)d_ws;
    float* bias  = (float*)((char*)d_ws + WT_BYTES);
    lstm_pack_w_v1<<<dim3(128, 64), 256, 0, stream>>>(Wxi, Whi, Wxf, Whf, Wxg, Whg, Wxo, Who, Wt);
    lstm_pack_bias_v1<<<16, 256, 0, stream>>>(bxi, bhi, bxf, bhf, bxg, bhg, bxo, bho, bias);
    lstm_gemm_v1<<<2048, 256, 0, stream>>>(x, h, c, Wt, bias, out);
  }
}

// Round 11
// 137.625 us; speedup vs baseline: 7.0926x; 7.0926x over previous
//
#include <hip/hip_runtime.h>
#include <stdint.h>

// LSTM cell: B=8192, DIN=1024, DOUT=1024, fp32 in/out.
// R11: int8 MFMA (16x16x64_i8, 2x bf16 rate, int32 exact accumulate).
// Quantization: symmetric i8, per-ROW scales for [x|h], per-COLUMN scales
// for packed W (Gaussian data -> absolute quant beats fp8's relative).
// GEMM = R6's validated 4-phase calendar; LDS tiles [256 rows][64 bytes]
// with R10's correctness-verified swizzle pair:
//   read chunk:  phys = l4 ^ ((l15>>1)&3)   (16B chunks, 2-way = free)
//   stage src :  k-chunk = (tid&3) ^ ((tid>>3)&3)  (matching involution)
// Calendar (tiles t=2i->buf0, u=2i+1->buf1, v=2i+2, w=2i+3):
//   Ph0: STA(1,u); read B(buf0)+A0(buf0); LG0; 16 MFMA; BAR
//   Ph1: STB(0,v); read A1(buf0);         LG0; 16 MFMA; VMC(2|0); BAR
//   Ph2: STA(0,v); read B(buf1)+A0(buf1); LG0; 16 MFMA; BAR
//   Ph3: STB(1,w); read A1(buf1);         LG0; 16 MFMA; VMC(2); BAR
// WAR: stage target's last reader drained by previous phase's LG0+BAR.
// RAW: Ph1-end queue = B(u)2,A(u)2,B(v)2 -> VMC(2) completes tile u;
//      Ph3-end queue = B(v)2,A(v)2,B(w)2 -> VMC(2) completes tile v.
// Epilogue: z = sx[row]*sw[col]*(float)acc + bias -> LSTM gates.

typedef __attribute__((ext_vector_type(4))) int i32x4;
typedef __attribute__((ext_vector_type(8))) _Float16 half8;
typedef __attribute__((ext_vector_type(4))) _Float16 half4;
typedef __attribute__((ext_vector_type(4))) float f32x4;

__device__ __forceinline__ void gload_lds16(const void* g, void* l) {
  __builtin_amdgcn_global_load_lds(
      (const __attribute__((address_space(1))) void*)g,
      (__attribute__((address_space(3))) void*)l, 16, 0, 0);
}

__device__ __forceinline__ float sigf(float x) { return 1.0f / (1.0f + __expf(-x)); }
__device__ __forceinline__ float tanhf_(float x) { return 1.0f - 2.0f / (__expf(2.0f * x) + 1.0f); }
__device__ __forceinline__ int q8(float v, float s) {
  int q = (int)rintf(v * s);
  return q < -127 ? -127 : (q > 127 ? 127 : q);
}

#define FENCE asm volatile("" ::: "memory")
#define BAR do { FENCE; __builtin_amdgcn_s_barrier(); FENCE; } while (0)
#define LG0 do { asm volatile("s_waitcnt lgkmcnt(0)" ::: "memory"); \
                 __builtin_amdgcn_sched_barrier(0); } while (0)
#define VMC(n) asm volatile("s_waitcnt vmcnt(" #n ")" ::: "memory")

// ---------------- scales kernel ----------------
// blocks [0,2048): row-max of [x|h] (4 rows/block, wave per row)
// blocks [2048,2112): col-max of packed W (64 cols/block, 4-way k-split)
__global__ void lstm_scales(const float* __restrict__ x, const float* __restrict__ h,
                            const float* __restrict__ Wxi, const float* __restrict__ Whi,
                            const float* __restrict__ Wxf, const float* __restrict__ Whf,
                            const float* __restrict__ Wxg, const float* __restrict__ Whg,
                            const float* __restrict__ Wxo, const float* __restrict__ Who,
                            float* __restrict__ sxd, float* __restrict__ sxq,
                            float* __restrict__ swd, float* __restrict__ swq) {
  int b = blockIdx.x, t = threadIdx.x;
  if (b < 2048) {
    int row = b * 4 + (t >> 6), l = t & 63;
    const float* px = x + (size_t)row * 1024;
    const float* ph = h + (size_t)row * 1024;
    float m = 0.f;
    #pragma unroll
    for (int i = 0; i < 16; ++i) {
      m = fmaxf(m, fabsf(px[l + 64 * i]));
      m = fmaxf(m, fabsf(ph[l + 64 * i]));
    }
    #pragma unroll
    for (int off = 32; off; off >>= 1) m = fmaxf(m, __shfl_xor(m, off));
    if (l == 0) {
      m = fmaxf(m, 1e-12f);
      sxd[row] = m / 127.f;
      sxq[row] = 127.f / m;
    }
  } else {
    __shared__ float red[4][64];
    int np = (b - 2048) * 64 + (t & 63);
    int ks = t >> 6;
    int g = (np >> 4) & 3, j = ((np >> 6) << 4) | (np & 15);
    const float* Wx[4] = {Wxi, Wxf, Wxg, Wxo};
    const float* Wh[4] = {Whi, Whf, Whg, Who};
    const float* A = Wx[g];
    const float* Bm = Wh[g];
    float m = 0.f;
    for (int kk = 0; kk < 256; ++kk) {
      int k = ks * 256 + kk;
      m = fmaxf(m, fabsf(A[(size_t)k * 1024 + j]));
      m = fmaxf(m, fabsf(Bm[(size_t)k * 1024 + j]));
    }
    red[ks][t & 63] = m;
    __syncthreads();
    if (ks == 0) {
      m = fmaxf(fmaxf(red[0][t], red[1][t]), fmaxf(red[2][t], red[3][t]));
      m = fmaxf(m, 1e-12f);
      swd[np] = m / 127.f;
      swq[np] = 127.f / m;
    }
  }
}

// ---------------- pack kernel ----------------
// blocks [0,8192): Wt i8 pack (32x32 tile transpose + quant)
// blocks [8192,16384): Xh i8 pack (one row/block)
// blocks [16384,16400): bias
// Wt[n'][k] i8, n' = (j>>4)*64 + g*16 + (j&15); k<1024 -> Wx_g[k][j], else Wh_g.
__global__ void lstm_pack_i8(const float* __restrict__ x, const float* __restrict__ h,
                             const float* __restrict__ Wxi, const float* __restrict__ Whi,
                             const float* __restrict__ Wxf, const float* __restrict__ Whf,
                             const float* __restrict__ Wxg, const float* __restrict__ Whg,
                             const float* __restrict__ Wxo, const float* __restrict__ Who,
                             const float* __restrict__ bxi, const float* __restrict__ bhi,
                             const float* __restrict__ bxf, const float* __restrict__ bhf,
                             const float* __restrict__ bxg, const float* __restrict__ bhg,
                             const float* __restrict__ bxo, const float* __restrict__ bho,
                             const float* __restrict__ sxq, const float* __restrict__ swq,
                             signed char* __restrict__ Wt, signed char* __restrict__ Xh,
                             float* __restrict__ bias) {
  __shared__ float tile[32][33];
  int b = blockIdx.x, t = threadIdx.x;
  if (b < 8192) {
    int nt = b & 127, kt = b >> 7;
    int g = nt & 3, jt32 = nt >> 2;
    const float* Wx[4] = {Wxi, Wxf, Wxg, Wxo};
    const float* Wh[4] = {Whi, Whf, Whg, Who};
    int k0 = kt * 32;
    const float* src = (k0 < 1024) ? (Wx[g] + (size_t)k0 * 1024)
                                   : (Wh[g] + (size_t)(k0 - 1024) * 1024);
    int j0 = jt32 * 32;
    int cc = t & 31, r0 = t >> 5;
    #pragma unroll
    for (int p = 0; p < 4; ++p) {
      int r = p * 8 + r0;
      tile[r][cc] = src[(size_t)r * 1024 + j0 + cc];
    }
    __syncthreads();
    int jj = t >> 3, kk = (t & 7) * 4;
    int j = j0 + jj;
    int np = ((j >> 4) << 6) + g * 16 + (j & 15);
    float sq = swq[np];
    uint32_t w = 0;
    #pragma unroll
    for (int e = 0; e < 4; ++e) {
      int q = q8(tile[kk + e][jj], sq);
      w |= ((uint32_t)(q & 0xFF)) << (8 * e);
    }
    *(uint32_t*)(Wt + (size_t)np * 2048 + k0 + kk) = w;
  } else if (b < 16384) {
    int row = b - 8192;
    float sq = sxq[row];
    int k = t * 8;
    const float* src = (k < 1024) ? (x + (size_t)row * 1024 + k)
                                  : (h + (size_t)row * 1024 + (k - 1024));
    float4 f0 = *(const float4*)src;
    float4 f1 = *(const float4*)(src + 4);
    float v[8] = {f0.x, f0.y, f0.z, f0.w, f1.x, f1.y, f1.z, f1.w};
    uint64_t w = 0;
    #pragma unroll
    for (int e = 0; e < 8; ++e) {
      int q = q8(v[e], sq);
      w |= ((uint64_t)(uint32_t)(q & 0xFF)) << (8 * e);
    }
    *(uint64_t*)(Xh + (size_t)row * 2048 + k) = w;
  } else {
    int tt = (b - 16384) * 256 + t;
    if (tt < 4096) {
      const float* bx[4] = {bxi, bxf, bxg, bxo};
      const float* bh[4] = {bhi, bhf, bhg, bho};
      int q = tt >> 4, r = tt & 15;
      int g = q & 3, j = (q >> 2) * 16 + r;
      bias[tt] = bx[g][j] + bh[g][j];
    }
  }
}

// ---------------- 4-phase i8 fused GEMM ----------------
__global__ __launch_bounds__(512, 2) void lstm_gemm_i8(
    const signed char* __restrict__ Xh, const signed char* __restrict__ Wt,
    const float* __restrict__ c, const float* __restrict__ bias,
    const float* __restrict__ sxd, const float* __restrict__ swd,
    float* __restrict__ out) {
  __shared__ signed char sA[2][256 * 64];   // 16KB x2
  __shared__ signed char sB[2][256 * 64];   // 16KB x2

  int bid = blockIdx.x;                 // 512 blocks
  int xcd = bid & 7, idx = bid >> 3;
  int mt = (xcd >> 1) * 8 + (idx >> 3); // 0..31
  int jt = (xcd & 1) * 8 + (idx & 7);   // 0..15
  int brow0 = mt * 256, bcol0 = jt * 256;

  int tid = threadIdx.x, lane = tid & 63, wave = tid >> 6;
  int wr = wave >> 2, wc = wave & 3;
  int l15 = lane & 15, l4 = lane >> 4;

  i32x4 acc[8][4] = {};                 // [m-frag 0..7][gate], int32

  int roff = (l4 ^ ((l15 >> 1) & 3)) * 16;   // byte offset of 16B chunk
  int aoff0 = (wr * 128 + l15) * 64;
  int boff0 = (wc * 64 + l15) * 64;
  int ssl = ((tid & 3) ^ ((tid >> 3) & 3)) * 16;  // stage source k-chunk bytes
  int srow = tid >> 2;                  // 0..127 per call

  auto stA = [&](int buf, int t, int a) {
    const signed char* src = Xh + (size_t)(brow0 + a * 128 + srow) * 2048 + t * 64 + ssl;
    gload_lds16(src, &sA[buf][(a * 128 + wave * 16) * 64]);
  };
  auto stB = [&](int buf, int t, int a) {
    const signed char* src = Wt + (size_t)(bcol0 + a * 128 + srow) * 2048 + t * 64 + ssl;
    gload_lds16(src, &sB[buf][(a * 128 + wave * 16) * 64]);
  };

#define STA(buf, t) do { stA(buf, t, 0); stA(buf, t, 1); } while (0)
#define STB(buf, t) do { stB(buf, t, 0); stB(buf, t, 1); } while (0)

#define LDBA(BUF) do { _Pragma("unroll") for (int nf = 0; nf < 4; ++nf) \
    bf[nf] = *(const i32x4*)&sB[BUF][boff0 + nf * 16 * 64 + roff]; } while (0)
#define LDAH(mh, BUF) do { _Pragma("unroll") for (int mi = 0; mi < 4; ++mi) \
    af[mi] = *(const i32x4*)&sA[BUF][aoff0 + ((mh) * 4 + mi) * 16 * 64 + roff]; } while (0)
#define MMH(mh) do {                                                          \
    __builtin_amdgcn_s_setprio(1);                                            \
    _Pragma("unroll") for (int mi = 0; mi < 4; ++mi)                          \
    _Pragma("unroll") for (int nf = 0; nf < 4; ++nf)                          \
      acc[(mh) * 4 + mi][nf] = __builtin_amdgcn_mfma_i32_16x16x64_i8(         \
          af[mi], bf[nf], acc[(mh) * 4 + mi][nf], 0, 0, 0);                   \
    __builtin_amdgcn_s_setprio(0); } while (0)

  // Prologue: tile0 (A+B) -> buf0, tile1 B -> buf1; complete tile0.
  STA(0, 0); STB(0, 0); STB(1, 1);
  VMC(2);                               // queue A(0)2,B(0)2,B(1)2 -> tile0 done
  BAR;

  i32x4 af[4], bf[4];

#pragma unroll 1
  for (int i = 0; i < 16; ++i) {
    const int u = 2 * i + 1, v = 2 * i + 2, w = 2 * i + 3;
    const bool pf = (i < 15);

    // Ph0: buf0 mh0.  Stage A(u)->buf1.
    STA(1, u);
    LDBA(0); LDAH(0, 0);
    LG0; MMH(0);
    BAR;
    // Ph1: buf0 mh1.  Stage B(v)->buf0.  Publish tile u.
    if (pf) STB(0, v);
    LDAH(1, 0);
    LG0; MMH(1);
    if (pf) { VMC(2); }
    else    { VMC(0); }
    BAR;
    // Ph2: buf1 mh0.  Stage A(v)->buf0.
    if (pf) STA(0, v);
    LDBA(1); LDAH(0, 1);
    LG0; MMH(0);
    BAR;
    // Ph3: buf1 mh1.  Stage B(w)->buf1.  Publish tile v.
    if (pf) STB(1, w);
    LDAH(1, 1);
    LG0; MMH(1);
    if (pf) { VMC(2); }
    BAR;
  }
#undef STA
#undef STB
#undef LDBA
#undef LDAH
#undef MMH

  // ---- fused LSTM epilogue: z = sx[row]*sw[col]*acc + bias ----
  int j = jt * 64 + wc * 16 + l15;
  int nbase = bcol0 + wc * 64 + l15;
  float sw0 = swd[nbase + 0];
  float sw1 = swd[nbase + 16];
  float sw2 = swd[nbase + 32];
  float sw3 = swd[nbase + 48];
  float bi  = bias[nbase + 0];
  float bff = bias[nbase + 16];
  float bg  = bias[nbase + 32];
  float bo  = bias[nbase + 48];
  float* hout = out;
  float* cout = out + (size_t)8192 * 1024;
  #pragma unroll
  for (int m = 0; m < 8; ++m) {
    #pragma unroll
    for (int r = 0; r < 4; ++r) {
      int grow = brow0 + wr * 128 + m * 16 + l4 * 4 + r;
      float sx = sxd[grow];
      size_t o = (size_t)grow * 1024 + j;
      float zi = (float)acc[m][0][r] * (sx * sw0) + bi;
      float zf = (float)acc[m][1][r] * (sx * sw1) + bff;
      float zg = (float)acc[m][2][r] * (sx * sw2) + bg;
      float zo = (float)acc[m][3][r] * (sx * sw3) + bo;
      float ig = sigf(zi);
      float fg = sigf(zf);
      float gg = tanhf_(zg);
      float og = sigf(zo);
      float cold = c[o];
      float cn = fg * cold + ig * gg;
      hout[o] = og * tanhf_(cn);
      cout[o] = cn;
    }
  }
}

// ---------------- fallback path (round-1, validated fp16) ----------------

__global__ void lstm_pack_w_v1(const float* __restrict__ Wxi, const float* __restrict__ Whi,
                               const float* __restrict__ Wxf, const float* __restrict__ Whf,
                               const float* __restrict__ Wxg, const float* __restrict__ Whg,
                               const float* __restrict__ Wxo, const float* __restrict__ Who,
                               _Float16* __restrict__ Wt) {
  __shared__ float tile[32][33];
  int nt = blockIdx.x;
  int kt = blockIdx.y;
  int g = nt & 3, jt = nt >> 2;
  const float* Wx[4] = {Wxi, Wxf, Wxg, Wxo};
  const float* Wh[4] = {Whi, Whf, Whg, Who};
  int k0 = kt * 32;
  const float* src = (k0 < 1024) ? (Wx[g] + (size_t)k0 * 1024)
                                 : (Wh[g] + (size_t)(k0 - 1024) * 1024);
  int j0 = jt * 32;
  int t = threadIdx.x;
  int cc = t & 31, r0 = t >> 5;
  #pragma unroll
  for (int p = 0; p < 4; ++p) {
    int r = p * 8 + r0;
    tile[r][cc] = src[(size_t)r * 1024 + j0 + cc];
  }
  __syncthreads();
  int jj = t >> 3, kk = (t & 7) * 4;
  half4 v;
  v[0] = (_Float16)tile[kk + 0][jj];
  v[1] = (_Float16)tile[kk + 1][jj];
  v[2] = (_Float16)tile[kk + 2][jj];
  v[3] = (_Float16)tile[kk + 3][jj];
  _Float16* dst = Wt + (size_t)(nt * 32 + jj) * 2048 + k0 + kk;
  *(half4*)dst = v;
}

__global__ void lstm_pack_bias_v1(const float* __restrict__ bxi, const float* __restrict__ bhi,
                                  const float* __restrict__ bxf, const float* __restrict__ bhf,
                                  const float* __restrict__ bxg, const float* __restrict__ bhg,
                                  const float* __restrict__ bxo, const float* __restrict__ bho,
                                  float* __restrict__ bias) {
  int t = blockIdx.x * 256 + threadIdx.x;
  if (t >= 4096) return;
  const float* bx[4] = {bxi, bxf, bxg, bxo};
  const float* bh[4] = {bhi, bhf, bhg, bho};
  int jt = t >> 7, g = (t >> 5) & 3, jj = t & 31;
  int j = jt * 32 + jj;
  bias[t] = bx[g][j] + bh[g][j];
}

__global__ __launch_bounds__(256, 2) void lstm_gemm_v1(
    const float* __restrict__ x, const float* __restrict__ h, const float* __restrict__ c,
    const _Float16* __restrict__ Wt, const float* __restrict__ bias,
    float* __restrict__ out) {
  __shared__ ushort sA[128 * 64];
  __shared__ ushort sB[128 * 64];
  int bid = blockIdx.x;
  int sbid = (bid & 7) * 256 + (bid >> 3);
  int mt = sbid >> 5, jt = sbid & 31;
  int brow0 = mt * 128;
  int tid = threadIdx.x;
  int lane = tid & 63, wave = tid >> 6;
  int wr = wave >> 1, wc = wave & 1;
  f32x4 acc[4][4] = {};
  int ar = tid >> 3;
  int as = tid & 7;
  int l3 = lane >> 3, l7w = lane & 7;
  int bsw = ((l7w ^ l3) << 3);
  int l15 = lane & 15, l4 = lane >> 4, l7 = lane & 7;
  for (int kt = 0; kt < 32; ++kt) {
    int k0 = kt * 64;
    const float* asrc = (k0 < 1024) ? (x + k0) : (h + (k0 - 1024));
    #pragma unroll
    for (int stp = 0; stp < 4; ++stp) {
      int row = stp * 32 + ar;
      const float* p = asrc + (size_t)(brow0 + row) * 1024 + as * 8;
      float4 f0 = *(const float4*)p;
      float4 f1 = *(const float4*)(p + 4);
      half8 hv;
      hv[0] = (_Float16)f0.x; hv[1] = (_Float16)f0.y;
      hv[2] = (_Float16)f0.z; hv[3] = (_Float16)f0.w;
      hv[4] = (_Float16)f1.x; hv[5] = (_Float16)f1.y;
      hv[6] = (_Float16)f1.z; hv[7] = (_Float16)f1.w;
      *(half8*)&sA[row * 64 + ((as ^ (row & 7)) << 3)] = hv;
    }
    #pragma unroll
    for (int ccall = 0; ccall < 4; ++ccall) {
      int rowbase = ccall * 32 + wave * 8;
      int grow = jt * 128 + rowbase + l3;
      const _Float16* src = Wt + (size_t)grow * 2048 + k0 + bsw;
      gload_lds16(src, &sB[rowbase * 64]);
    }
    __syncthreads();
    #pragma unroll
    for (int ks = 0; ks < 2; ++ks) {
      half8 af[4], bfr[4];
      #pragma unroll
      for (int mi = 0; mi < 4; ++mi) {
        int row = wr * 64 + mi * 16 + l15;
        af[mi] = *(const half8*)&sA[row * 64 + (((ks * 4 + l4) ^ l7) << 3)];
      }
      #pragma unroll
      for (int g = 0; g < 4; ++g) {
        int nr = g * 32 + wc * 16 + l15;
        bfr[g] = *(const half8*)&sB[nr * 64 + (((ks * 4 + l4) ^ l7) << 3)];
      }
      #pragma unroll
      for (int mi = 0; mi < 4; ++mi)
        #pragma unroll
        for (int g = 0; g < 4; ++g)
          acc[mi][g] = __builtin_amdgcn_mfma_f32_16x16x32_f16(af[mi], bfr[g], acc[mi][g], 0, 0, 0);
    }
    __syncthreads();
  }
  int j = jt * 32 + wc * 16 + l15;
  int nb = jt * 128 + wc * 16 + l15;
  float bi  = bias[nb + 0];
  float bff = bias[nb + 32];
  float bg  = bias[nb + 64];
  float bo  = bias[nb + 96];
  float* hout = out;
  float* cout = out + (size_t)8192 * 1024;
  #pragma unroll
  for (int mi = 0; mi < 4; ++mi) {
    #pragma unroll
    for (int r = 0; r < 4; ++r) {
      int grow = brow0 + wr * 64 + mi * 16 + l4 * 4 + r;
      size_t idx = (size_t)grow * 1024 + j;
      float zi = acc[mi][0][r] + bi;
      float zf = acc[mi][1][r] + bff;
      float zg = acc[mi][2][r] + bg;
      float zo = acc[mi][3][r] + bo;
      float ig = sigf(zi);
      float fg = sigf(zf);
      float gg = tanhf_(zg);
      float og = sigf(zo);
      float cold = c[idx];
      float cn = fg * cold + ig * gg;
      hout[idx] = og * tanhf_(cn);
      cout[idx] = cn;
    }
  }
}

extern "C" void kernel_launch(void* const* d_in, const int* in_sizes, int n_in,
                              void* d_out, int out_size, void* d_ws, size_t ws_size,
                              hipStream_t stream) {
  const float* x   = (const float*)d_in[0];
  const float* h   = (const float*)d_in[1];
  const float* c   = (const float*)d_in[2];
  const float* Wxi = (const float*)d_in[3];
  const float* Whi = (const float*)d_in[4];
  const float* bxi = (const float*)d_in[5];
  const float* bhi = (const float*)d_in[6];
  const float* Wxf = (const float*)d_in[7];
  const float* Whf = (const float*)d_in[8];
  const float* bxf = (const float*)d_in[9];
  const float* bhf = (const float*)d_in[10];
  const float* Wxg = (const float*)d_in[11];
  const float* Whg = (const float*)d_in[12];
  const float* bxg = (const float*)d_in[13];
  const float* bhg = (const float*)d_in[14];
  const float* Wxo = (const float*)d_in[15];
  const float* Who = (const float*)d_in[16];
  const float* bxo = (const float*)d_in[17];
  const float* bho = (const float*)d_in[18];
  float* out = (float*)d_out;

  // i8 ws layout
  const size_t WT_B  = (size_t)4096 * 2048;          // 8 MiB
  const size_t XH_B  = (size_t)8192 * 2048;          // 16 MiB
  const size_t NEED = WT_B + XH_B + 4096 * 4 + 8192 * 8 + 4096 * 8;

  if (ws_size >= NEED) {
    signed char* Wt = (signed char*)d_ws;
    signed char* Xh = (signed char*)d_ws + WT_B;
    char* p = (char*)d_ws + WT_B + XH_B;
    float* bias = (float*)p;             p += 4096 * 4;
    float* sxd  = (float*)p;             p += 8192 * 4;
    float* sxq  = (float*)p;             p += 8192 * 4;
    float* swd  = (float*)p;             p += 4096 * 4;
    float* swq  = (float*)p;
    lstm_scales<<<2112, 256, 0, stream>>>(x, h, Wxi, Whi, Wxf, Whf, Wxg, Whg,
                                          Wxo, Who, sxd, sxq, swd, swq);
    lstm_pack_i8<<<16400, 256, 0, stream>>>(x, h, Wxi, Whi, Wxf, Whf, Wxg, Whg,
                                            Wxo, Who, bxi, bhi, bxf, bhf,
                                            bxg, bhg, bxo, bho, sxq, swq,
                                            Wt, Xh, bias);
    lstm_gemm_i8<<<512, 512, 0, stream>>>(Xh, Wt, c, bias, sxd, swd, out);
  } else {
    _Float16* Wt = (_Float16*)d_ws;
    float* bias  = (float*)((char*)d_ws + (size_t)4096 * 2048 * 2);
    lstm_pack_w_v1<<<dim3(128, 64), 256, 0, stream>>>(Wxi, Whi, Wxf, Whf, Wxg, Whg, Wxo, Who, Wt);
    lstm_pack_bias_v1<<<16, 256, 0, stream>>>(bxi, bhi, bxf, bhf, bxg, bhg, bxo, bho, bias);
    lstm_gemm_v1<<<2048, 256, 0, stream>>>(x, h, c, Wt, bias, out);
  }
}

// Round 12
// 133.226 us; speedup vs baseline: 7.3268x; 1.0330x over previous
//
#include <hip/hip_runtime.h>
#include <stdint.h>

// LSTM cell: B=8192, DIN=1024, DOUT=1024, fp32 in/out.
// R12: R11's validated i8 GEMM (byte-identical schedule) + rebuilt pre-pass:
//  1) lstm_colmax: coalesced W sweep, per-col |max| via LDS + atomicMax(uint
//     bits of positive floats) into colmax[4096] (np-indexed). Zeroed by
//     hipMemsetAsync (stream-ordered).
//  2) lstm_quant: ONE-pass x|h row quant (block reduce max -> quantize from
//     registers), W pack with swq=127/colmax inline, bias.
//  3) GEMM epilogue derives sw from colmax * (1/127).
// i8 numerics: symmetric, per-row (x|h) x per-col (W) scales; int32 exact acc.

typedef __attribute__((ext_vector_type(4))) int i32x4;
typedef __attribute__((ext_vector_type(8))) _Float16 half8;
typedef __attribute__((ext_vector_type(4))) _Float16 half4;
typedef __attribute__((ext_vector_type(4))) float f32x4;

__device__ __forceinline__ void gload_lds16(const void* g, void* l) {
  __builtin_amdgcn_global_load_lds(
      (const __attribute__((address_space(1))) void*)g,
      (__attribute__((address_space(3))) void*)l, 16, 0, 0);
}

__device__ __forceinline__ float sigf(float x) { return 1.0f / (1.0f + __expf(-x)); }
__device__ __forceinline__ float tanhf_(float x) { return 1.0f - 2.0f / (__expf(2.0f * x) + 1.0f); }
__device__ __forceinline__ int q8(float v, float s) {
  int q = (int)rintf(v * s);
  return q < -127 ? -127 : (q > 127 ? 127 : q);
}

#define FENCE asm volatile("" ::: "memory")
#define BAR do { FENCE; __builtin_amdgcn_s_barrier(); FENCE; } while (0)
#define LG0 do { asm volatile("s_waitcnt lgkmcnt(0)" ::: "memory"); \
                 __builtin_amdgcn_sched_barrier(0); } while (0)
#define VMC(n) asm volatile("s_waitcnt vmcnt(" #n ")" ::: "memory")

// ---------------- col-max kernel (coalesced) ----------------
// 512 blocks: matrix m = b>>6 (0..3 Wx_g, 4..7 Wh_g), rows (b&63)*16..+16.
// np = ((j>>4)<<6) + g*16 + (j&15),  g = m&3.
__global__ void lstm_colmax(const float* __restrict__ Wxi, const float* __restrict__ Wxf,
                            const float* __restrict__ Wxg, const float* __restrict__ Wxo,
                            const float* __restrict__ Whi, const float* __restrict__ Whf,
                            const float* __restrict__ Whg, const float* __restrict__ Who,
                            unsigned int* __restrict__ colmax) {
  __shared__ float cm[1024];
  int b = blockIdx.x, t = threadIdx.x;
  int m = b >> 6;
  int r0 = (b & 63) * 16;
  const float* Ws[8] = {Wxi, Wxf, Wxg, Wxo, Whi, Whf, Whg, Who};
  const float* src = Ws[m] + (size_t)r0 * 1024;
  #pragma unroll
  for (int i = 0; i < 4; ++i) cm[t + 256 * i] = 0.f;
  __syncthreads();
  for (int r = 0; r < 16; ++r) {
    #pragma unroll
    for (int c4 = 0; c4 < 4; ++c4) {
      int col = t + 256 * c4;
      float v = fabsf(src[(size_t)r * 1024 + col]);
      cm[col] = fmaxf(cm[col], v);
    }
  }
  __syncthreads();
  int g = m & 3;
  #pragma unroll
  for (int i = 0; i < 4; ++i) {
    int j = t + 256 * i;
    int np = ((j >> 4) << 6) + g * 16 + (j & 15);
    atomicMax(&colmax[np], __float_as_uint(cm[j]));
  }
}

// ---------------- quant/pack kernel ----------------
// blocks [0,8192): one-pass x|h row quant (row = b)
// blocks [8192,16384): W pack (swq from colmax)
// blocks [16384,16400): bias
__global__ void lstm_quant(const float* __restrict__ x, const float* __restrict__ h,
                           const float* __restrict__ Wxi, const float* __restrict__ Whi,
                           const float* __restrict__ Wxf, const float* __restrict__ Whf,
                           const float* __restrict__ Wxg, const float* __restrict__ Whg,
                           const float* __restrict__ Wxo, const float* __restrict__ Who,
                           const float* __restrict__ bxi, const float* __restrict__ bhi,
                           const float* __restrict__ bxf, const float* __restrict__ bhf,
                           const float* __restrict__ bxg, const float* __restrict__ bhg,
                           const float* __restrict__ bxo, const float* __restrict__ bho,
                           const unsigned int* __restrict__ colmax,
                           signed char* __restrict__ Wt, signed char* __restrict__ Xh,
                           float* __restrict__ bias, float* __restrict__ sxd) {
  int b = blockIdx.x, t = threadIdx.x;
  if (b < 8192) {
    __shared__ float wm[4];
    int row = b;
    int k = t * 8;
    const float* src = (k < 1024) ? (x + (size_t)row * 1024 + k)
                                  : (h + (size_t)row * 1024 + (k - 1024));
    float4 f0 = *(const float4*)src;
    float4 f1 = *(const float4*)(src + 4);
    float v[8] = {f0.x, f0.y, f0.z, f0.w, f1.x, f1.y, f1.z, f1.w};
    float m = 0.f;
    #pragma unroll
    for (int e = 0; e < 8; ++e) m = fmaxf(m, fabsf(v[e]));
    #pragma unroll
    for (int off = 32; off; off >>= 1) m = fmaxf(m, __shfl_xor(m, off));
    if ((t & 63) == 0) wm[t >> 6] = m;
    __syncthreads();
    m = fmaxf(fmaxf(wm[0], wm[1]), fmaxf(wm[2], wm[3]));
    m = fmaxf(m, 1e-12f);
    float sq = 127.f / m;
    uint64_t w = 0;
    #pragma unroll
    for (int e = 0; e < 8; ++e) {
      int q = q8(v[e], sq);
      w |= ((uint64_t)(uint32_t)(q & 0xFF)) << (8 * e);
    }
    *(uint64_t*)(Xh + (size_t)row * 2048 + k) = w;
    if (t == 0) sxd[row] = m * (1.f / 127.f);
  } else if (b < 16384) {
    __shared__ float tile[32][33];
    int bb = b - 8192;
    int nt = bb & 127, kt = bb >> 7;
    int g = nt & 3, jt32 = nt >> 2;
    const float* Wx[4] = {Wxi, Wxf, Wxg, Wxo};
    const float* Wh[4] = {Whi, Whf, Whg, Who};
    int k0 = kt * 32;
    const float* src = (k0 < 1024) ? (Wx[g] + (size_t)k0 * 1024)
                                   : (Wh[g] + (size_t)(k0 - 1024) * 1024);
    int j0 = jt32 * 32;
    int cc = t & 31, r0 = t >> 5;
    #pragma unroll
    for (int p = 0; p < 4; ++p) {
      int r = p * 8 + r0;
      tile[r][cc] = src[(size_t)r * 1024 + j0 + cc];
    }
    __syncthreads();
    int jj = t >> 3, kk = (t & 7) * 4;
    int j = j0 + jj;
    int np = ((j >> 4) << 6) + g * 16 + (j & 15);
    float mw = fmaxf(__uint_as_float(colmax[np]), 1e-12f);
    float sq = 127.f / mw;
    uint32_t w = 0;
    #pragma unroll
    for (int e = 0; e < 4; ++e) {
      int q = q8(tile[kk + e][jj], sq);
      w |= ((uint32_t)(q & 0xFF)) << (8 * e);
    }
    *(uint32_t*)(Wt + (size_t)np * 2048 + k0 + kk) = w;
  } else {
    int tt = (b - 16384) * 256 + t;
    if (tt < 4096) {
      const float* bx[4] = {bxi, bxf, bxg, bxo};
      const float* bh[4] = {bhi, bhf, bhg, bho};
      int q = tt >> 4, r = tt & 15;
      int g = q & 3, j = (q >> 2) * 16 + r;
      bias[tt] = bx[g][j] + bh[g][j];
    }
  }
}

// ---------------- 4-phase i8 fused GEMM (R11-validated schedule) ----------------
__global__ __launch_bounds__(512, 2) void lstm_gemm_i8(
    const signed char* __restrict__ Xh, const signed char* __restrict__ Wt,
    const float* __restrict__ c, const float* __restrict__ bias,
    const float* __restrict__ sxd, const unsigned int* __restrict__ colmax,
    float* __restrict__ out) {
  __shared__ signed char sA[2][256 * 64];
  __shared__ signed char sB[2][256 * 64];

  int bid = blockIdx.x;                 // 512 blocks
  int xcd = bid & 7, idx = bid >> 3;
  int mt = (xcd >> 1) * 8 + (idx >> 3); // 0..31
  int jt = (xcd & 1) * 8 + (idx & 7);   // 0..15
  int brow0 = mt * 256, bcol0 = jt * 256;

  int tid = threadIdx.x, lane = tid & 63, wave = tid >> 6;
  int wr = wave >> 2, wc = wave & 3;
  int l15 = lane & 15, l4 = lane >> 4;

  i32x4 acc[8][4] = {};

  int roff = (l4 ^ ((l15 >> 1) & 3)) * 16;
  int aoff0 = (wr * 128 + l15) * 64;
  int boff0 = (wc * 64 + l15) * 64;
  int ssl = ((tid & 3) ^ ((tid >> 3) & 3)) * 16;
  int srow = tid >> 2;

  auto stA = [&](int buf, int t, int a) {
    const signed char* src = Xh + (size_t)(brow0 + a * 128 + srow) * 2048 + t * 64 + ssl;
    gload_lds16(src, &sA[buf][(a * 128 + wave * 16) * 64]);
  };
  auto stB = [&](int buf, int t, int a) {
    const signed char* src = Wt + (size_t)(bcol0 + a * 128 + srow) * 2048 + t * 64 + ssl;
    gload_lds16(src, &sB[buf][(a * 128 + wave * 16) * 64]);
  };

#define STA(buf, t) do { stA(buf, t, 0); stA(buf, t, 1); } while (0)
#define STB(buf, t) do { stB(buf, t, 0); stB(buf, t, 1); } while (0)

#define LDBA(BUF) do { _Pragma("unroll") for (int nf = 0; nf < 4; ++nf) \
    bf[nf] = *(const i32x4*)&sB[BUF][boff0 + nf * 16 * 64 + roff]; } while (0)
#define LDAH(mh, BUF) do { _Pragma("unroll") for (int mi = 0; mi < 4; ++mi) \
    af[mi] = *(const i32x4*)&sA[BUF][aoff0 + ((mh) * 4 + mi) * 16 * 64 + roff]; } while (0)
#define MMH(mh) do {                                                          \
    __builtin_amdgcn_s_setprio(1);                                            \
    _Pragma("unroll") for (int mi = 0; mi < 4; ++mi)                          \
    _Pragma("unroll") for (int nf = 0; nf < 4; ++nf)                          \
      acc[(mh) * 4 + mi][nf] = __builtin_amdgcn_mfma_i32_16x16x64_i8(         \
          af[mi], bf[nf], acc[(mh) * 4 + mi][nf], 0, 0, 0);                   \
    __builtin_amdgcn_s_setprio(0); } while (0)

  // Prologue
  STA(0, 0); STB(0, 0); STB(1, 1);
  VMC(2);
  BAR;

  i32x4 af[4], bf[4];

#pragma unroll 1
  for (int i = 0; i < 16; ++i) {
    const int u = 2 * i + 1, v = 2 * i + 2, w = 2 * i + 3;
    const bool pf = (i < 15);

    STA(1, u);
    LDBA(0); LDAH(0, 0);
    LG0; MMH(0);
    BAR;

    if (pf) STB(0, v);
    LDAH(1, 0);
    LG0; MMH(1);
    if (pf) { VMC(2); }
    else    { VMC(0); }
    BAR;

    if (pf) STA(0, v);
    LDBA(1); LDAH(0, 1);
    LG0; MMH(0);
    BAR;

    if (pf) STB(1, w);
    LDAH(1, 1);
    LG0; MMH(1);
    if (pf) { VMC(2); }
    BAR;
  }
#undef STA
#undef STB
#undef LDBA
#undef LDAH
#undef MMH

  // ---- fused LSTM epilogue ----
  int j = jt * 64 + wc * 16 + l15;
  int nbase = bcol0 + wc * 64 + l15;
  const float inv127 = 1.f / 127.f;
  float sw0 = fmaxf(__uint_as_float(colmax[nbase + 0]),  1e-12f) * inv127;
  float sw1 = fmaxf(__uint_as_float(colmax[nbase + 16]), 1e-12f) * inv127;
  float sw2 = fmaxf(__uint_as_float(colmax[nbase + 32]), 1e-12f) * inv127;
  float sw3 = fmaxf(__uint_as_float(colmax[nbase + 48]), 1e-12f) * inv127;
  float bi  = bias[nbase + 0];
  float bff = bias[nbase + 16];
  float bg  = bias[nbase + 32];
  float bo  = bias[nbase + 48];
  float* hout = out;
  float* cout = out + (size_t)8192 * 1024;
  #pragma unroll
  for (int m = 0; m < 8; ++m) {
    #pragma unroll
    for (int r = 0; r < 4; ++r) {
      int grow = brow0 + wr * 128 + m * 16 + l4 * 4 + r;
      float sx = sxd[grow];
      size_t o = (size_t)grow * 1024 + j;
      float zi = (float)acc[m][0][r] * (sx * sw0) + bi;
      float zf = (float)acc[m][1][r] * (sx * sw1) + bff;
      float zg = (float)acc[m][2][r] * (sx * sw2) + bg;
      float zo = (float)acc[m][3][r] * (sx * sw3) + bo;
      float ig = sigf(zi);
      float fg = sigf(zf);
      float gg = tanhf_(zg);
      float og = sigf(zo);
      float cold = c[o];
      float cn = fg * cold + ig * gg;
      hout[o] = og * tanhf_(cn);
      cout[o] = cn;
    }
  }
}

// ---------------- fallback path (round-1, validated fp16) ----------------

__global__ void lstm_pack_w_v1(const float* __restrict__ Wxi, const float* __restrict__ Whi,
                               const float* __restrict__ Wxf, const float* __restrict__ Whf,
                               const float* __restrict__ Wxg, const float* __restrict__ Whg,
                               const float* __restrict__ Wxo, const float* __restrict__ Who,
                               _Float16* __restrict__ Wt) {
  __shared__ float tile[32][33];
  int nt = blockIdx.x;
  int kt = blockIdx.y;
  int g = nt & 3, jt = nt >> 2;
  const float* Wx[4] = {Wxi, Wxf, Wxg, Wxo};
  const float* Wh[4] = {Whi, Whf, Whg, Who};
  int k0 = kt * 32;
  const float* src = (k0 < 1024) ? (Wx[g] + (size_t)k0 * 1024)
                                 : (Wh[g] + (size_t)(k0 - 1024) * 1024);
  int j0 = jt * 32;
  int t = threadIdx.x;
  int cc = t & 31, r0 = t >> 5;
  #pragma unroll
  for (int p = 0; p < 4; ++p) {
    int r = p * 8 + r0;
    tile[r][cc] = src[(size_t)r * 1024 + j0 + cc];
  }
  __syncthreads();
  int jj = t >> 3, kk = (t & 7) * 4;
  half4 v;
  v[0] = (_Float16)tile[kk + 0][jj];
  v[1] = (_Float16)tile[kk + 1][jj];
  v[2] = (_Float16)tile[kk + 2][jj];
  v[3] = (_Float16)tile[kk + 3][jj];
  _Float16* dst = Wt + (size_t)(nt * 32 + jj) * 2048 + k0 + kk;
  *(half4*)dst = v;
}

__global__ void lstm_pack_bias_v1(const float* __restrict__ bxi, const float* __restrict__ bhi,
                                  const float* __restrict__ bxf, const float* __restrict__ bhf,
                                  const float* __restrict__ bxg, const float* __restrict__ bhg,
                                  const float* __restrict__ bxo, const float* __restrict__ bho,
                                  float* __restrict__ bias) {
  int t = blockIdx.x * 256 + threadIdx.x;
  if (t >= 4096) return;
  const float* bx[4] = {bxi, bxf, bxg, bxo};
  const float* bh[4] = {bhi, bhf, bhg, bho};
  int jt = t >> 7, g = (t >> 5) & 3, jj = t & 31;
  int j = jt * 32 + jj;
  bias[t] = bx[g][j] + bh[g][j];
}

__global__ __launch_bounds__(256, 2) void lstm_gemm_v1(
    const float* __restrict__ x, const float* __restrict__ h, const float* __restrict__ c,
    const _Float16* __restrict__ Wt, const float* __restrict__ bias,
    float* __restrict__ out) {
  __shared__ ushort sA[128 * 64];
  __shared__ ushort sB[128 * 64];
  int bid = blockIdx.x;
  int sbid = (bid & 7) * 256 + (bid >> 3);
  int mt = sbid >> 5, jt = sbid & 31;
  int brow0 = mt * 128;
  int tid = threadIdx.x;
  int lane = tid & 63, wave = tid >> 6;
  int wr = wave >> 1, wc = wave & 1;
  f32x4 acc[4][4] = {};
  int ar = tid >> 3;
  int as = tid & 7;
  int l3 = lane >> 3, l7w = lane & 7;
  int bsw = ((l7w ^ l3) << 3);
  int l15 = lane & 15, l4 = lane >> 4, l7 = lane & 7;
  for (int kt = 0; kt < 32; ++kt) {
    int k0 = kt * 64;
    const float* asrc = (k0 < 1024) ? (x + k0) : (h + (k0 - 1024));
    #pragma unroll
    for (int stp = 0; stp < 4; ++stp) {
      int row = stp * 32 + ar;
      const float* p = asrc + (size_t)(brow0 + row) * 1024 + as * 8;
      float4 f0 = *(const float4*)p;
      float4 f1 = *(const float4*)(p + 4);
      half8 hv;
      hv[0] = (_Float16)f0.x; hv[1] = (_Float16)f0.y;
      hv[2] = (_Float16)f0.z; hv[3] = (_Float16)f0.w;
      hv[4] = (_Float16)f1.x; hv[5] = (_Float16)f1.y;
      hv[6] = (_Float16)f1.z; hv[7] = (_Float16)f1.w;
      *(half8*)&sA[row * 64 + ((as ^ (row & 7)) << 3)] = hv;
    }
    #pragma unroll
    for (int ccall = 0; ccall < 4; ++ccall) {
      int rowbase = ccall * 32 + wave * 8;
      int grow = jt * 128 + rowbase + l3;
      const _Float16* src = Wt + (size_t)grow * 2048 + k0 + bsw;
      gload_lds16(src, &sB[rowbase * 64]);
    }
    __syncthreads();
    #pragma unroll
    for (int ks = 0; ks < 2; ++ks) {
      half8 af[4], bfr[4];
      #pragma unroll
      for (int mi = 0; mi < 4; ++mi) {
        int row = wr * 64 + mi * 16 + l15;
        af[mi] = *(const half8*)&sA[row * 64 + (((ks * 4 + l4) ^ l7) << 3)];
      }
      #pragma unroll
      for (int g = 0; g < 4; ++g) {
        int nr = g * 32 + wc * 16 + l15;
        bfr[g] = *(const half8*)&sB[nr * 64 + (((ks * 4 + l4) ^ l7) << 3)];
      }
      #pragma unroll
      for (int mi = 0; mi < 4; ++mi)
        #pragma unroll
        for (int g = 0; g < 4; ++g)
          acc[mi][g] = __builtin_amdgcn_mfma_f32_16x16x32_f16(af[mi], bfr[g], acc[mi][g], 0, 0, 0);
    }
    __syncthreads();
  }
  int j = jt * 32 + wc * 16 + l15;
  int nb = jt * 128 + wc * 16 + l15;
  float bi  = bias[nb + 0];
  float bff = bias[nb + 32];
  float bg  = bias[nb + 64];
  float bo  = bias[nb + 96];
  float* hout = out;
  float* cout = out + (size_t)8192 * 1024;
  #pragma unroll
  for (int mi = 0; mi < 4; ++mi) {
    #pragma unroll
    for (int r = 0; r < 4; ++r) {
      int grow = brow0 + wr * 64 + mi * 16 + l4 * 4 + r;
      size_t idx = (size_t)grow * 1024 + j;
      float zi = acc[mi][0][r] + bi;
      float zf = acc[mi][1][r] + bff;
      float zg = acc[mi][2][r] + bg;
      float zo = acc[mi][3][r] + bo;
      float ig = sigf(zi);
      float fg = sigf(zf);
      float gg = tanhf_(zg);
      float og = sigf(zo);
      float cold = c[idx];
      float cn = fg * cold + ig * gg;
      hout[idx] = og * tanhf_(cn);
      cout[idx] = cn;
    }
  }
}

extern "C" void kernel_launch(void* const* d_in, const int* in_sizes, int n_in,
                              void* d_out, int out_size, void* d_ws, size_t ws_size,
                              hipStream_t stream) {
  const float* x   = (const float*)d_in[0];
  const float* h   = (const float*)d_in[1];
  const float* c   = (const float*)d_in[2];
  const float* Wxi = (const float*)d_in[3];
  const float* Whi = (const float*)d_in[4];
  const float* bxi = (const float*)d_in[5];
  const float* bhi = (const float*)d_in[6];
  const float* Wxf = (const float*)d_in[7];
  const float* Whf = (const float*)d_in[8];
  const float* bxf = (const float*)d_in[9];
  const float* bhf = (const float*)d_in[10];
  const float* Wxg = (const float*)d_in[11];
  const float* Whg = (const float*)d_in[12];
  const float* bxg = (const float*)d_in[13];
  const float* bhg = (const float*)d_in[14];
  const float* Wxo = (const float*)d_in[15];
  const float* Who = (const float*)d_in[16];
  const float* bxo = (const float*)d_in[17];
  const float* bho = (const float*)d_in[18];
  float* out = (float*)d_out;

  const size_t WT_B = (size_t)4096 * 2048;           // 8 MiB
  const size_t XH_B = (size_t)8192 * 2048;           // 16 MiB
  const size_t NEED = WT_B + XH_B + 4096 * 4 + 8192 * 4 + 4096 * 4;

  if (ws_size >= NEED) {
    signed char* Wt = (signed char*)d_ws;
    signed char* Xh = (signed char*)d_ws + WT_B;
    char* p = (char*)d_ws + WT_B + XH_B;
    float* bias = (float*)p;               p += 4096 * 4;
    float* sxd  = (float*)p;               p += 8192 * 4;
    unsigned int* colmax = (unsigned int*)p;
    hipMemsetAsync(colmax, 0, 4096 * 4, stream);
    lstm_colmax<<<512, 256, 0, stream>>>(Wxi, Wxf, Wxg, Wxo, Whi, Whf, Whg, Who, colmax);
    lstm_quant<<<16400, 256, 0, stream>>>(x, h, Wxi, Whi, Wxf, Whf, Wxg, Whg,
                                          Wxo, Who, bxi, bhi, bxf, bhf,
                                          bxg, bhg, bxo, bho, colmax,
                                          Wt, Xh, bias, sxd);
    lstm_gemm_i8<<<512, 512, 0, stream>>>(Xh, Wt, c, bias, sxd, colmax, out);
  } else {
    _Float16* Wt = (_Float16*)d_ws;
    float* bias  = (float*)((char*)d_ws + (size_t)4096 * 2048 * 2);
    lstm_pack_w_v1<<<dim3(128, 64), 256, 0, stream>>>(Wxi, Whi, Wxf, Whf, Wxg, Whg, Wxo, Who, Wt);
    lstm_pack_bias_v1<<<16, 256, 0, stream>>>(bxi, bhi, bxf, bhf, bxg, bhg, bxo, bho, bias);
    lstm_gemm_v1<<<2048, 256, 0, stream>>>(x, h, c, Wt, bias, out);
  }
}